// Round 6
// baseline (305.821 us; speedup 1.0000x reference)
//
#include <hip/hip_runtime.h>
#include <hip/hip_bf16.h>

// MyGNN on MI355X — round 6.
//  prep: W1,W2,Wl,Wfi -> bf16 frag-ordered global (32KB each, L2-hot) + zero counts
//  K1:   fill_buckets (nt edge loads, LDS=0) ∪ gemm1(x1@W1->t1) ∪ br0(gather x0@Wfi->out0)
//  K2:   per 64-node tile: agg(t1)+b1 -> LDS -> @W2 -> t2          (fused agg1+gemm2)
//  K3:   per 64-slot tile: agg(t2)+b2 at selected nodes -> LDS -> @Wl + bl -> out1
// GEMMs: mfma_f32_16x16x32_bf16, fp32 accumulate; B-frags read straight from global.

#define B_    64
#define ADJ_  1000
#define N_    64000
#define E_    (1 << 20)
#define M_    32000
#define DV    128
#define CAP   64
#define RANGES 8
#define RSPAN  (N_ / RANGES)   // 8000
#define CHUNKS 512
#define EPB    (E_ / CHUNKS)   // 2048

typedef __attribute__((ext_vector_type(8))) short short8v;   // 8 bf16
typedef __attribute__((ext_vector_type(4))) float float4v;
typedef __attribute__((ext_vector_type(4))) int   int4v;

__device__ __forceinline__ float u2f(unsigned int u) {
  union { unsigned int i; float f; } x; x.i = u; return x.f;
}
__device__ __forceinline__ unsigned short f2bf(float f) {   // RNE
  union { float f; unsigned int i; } x; x.f = f;
  unsigned int r = x.i + 0x7fffu + ((x.i >> 16) & 1u);
  return (unsigned short)(r >> 16);
}
__device__ __forceinline__ unsigned int pack_bf2(float a, float b) {
  __hip_bfloat162 h = __float22bfloat162_rn(float2{a, b});
  union { __hip_bfloat162 h; unsigned int u; } c; c.h = h;
  return c.u;
}

// ---------------- prep: frag-order W -> bf16 global, zero counts ----------------
// frag addr: lane=(q*16+m), frag f=(nb*4+kc): wf[f*64*8 + lane*8 + j] = W[kc*32+q*8+j][nb*16+m]
__global__ __launch_bounds__(256)
void prep(const float* __restrict__ W1, const float* __restrict__ W2,
          const float* __restrict__ Wl, const float* __restrict__ Wfi,
          unsigned short* __restrict__ wf, int* __restrict__ counts) {
  int t = blockIdx.x * 256 + threadIdx.x;
  if (t < 4 * 16384) {
    int mtx = t >> 14, g = t & 16383;
    const float* W = mtx == 0 ? W1 : mtx == 1 ? W2 : mtx == 2 ? Wl : Wfi;
    int k = g >> 7, n = g & 127;
    int addr = ((((n >> 4) * 4 + (k >> 5)) * 64 + ((k >> 3) & 3) * 16 + (n & 15)) << 3)
             + (k & 7);
    wf[mtx * 16384 + addr] = f2bf(W[g]);
  } else {
    int c = t - 65536;
    if (c < N_) counts[c] = 0;
  }
}

// ---------------- fill part: chunk c, dst-range r (nt edge loads) ----------------
__device__ __forceinline__ void fill_part(const int* __restrict__ ei,
                                          int* __restrict__ counts,
                                          unsigned short* __restrict__ bucket,
                                          int c, int r) {
  const int* srcA = ei;
  const int* dstA = ei + E_;
  int lo = r * RSPAN;
  int t4 = c * EPB + (int)threadIdx.x * 4;
  int4v d0 = __builtin_nontemporal_load((const int4v*)(dstA + t4));
  int4v s0 = __builtin_nontemporal_load((const int4v*)(srcA + t4));
  int4v d1 = __builtin_nontemporal_load((const int4v*)(dstA + t4 + 1024));
  int4v s1 = __builtin_nontemporal_load((const int4v*)(srcA + t4 + 1024));
#define PROC(D, S) do {                                                \
    if ((unsigned)((D) - lo) < (unsigned)RSPAN) {                      \
      int pos = atomicAdd(&counts[(D)], 1);                            \
      if (pos < CAP) bucket[(size_t)(D) * CAP + pos] = (unsigned short)(S); \
    } } while (0)
  PROC(d0.x, s0.x); PROC(d0.y, s0.y); PROC(d0.z, s0.z); PROC(d0.w, s0.w);
  PROC(d1.x, s1.x); PROC(d1.y, s1.y); PROC(d1.z, s1.z); PROC(d1.w, s1.w);
#undef PROC
}

// ---------------- LDS-free MFMA GEMM tile (B-frags from global) ----------------
template<bool GATHER, bool OUTBF16, bool HASBIAS>
__device__ __forceinline__ void gemm_g(const float* __restrict__ in,
                                       const unsigned short* __restrict__ wf,
                                       const float* __restrict__ bias,
                                       void* __restrict__ out_, int tile,
                                       const int* __restrict__ bidx,
                                       const int* __restrict__ nidx) {
  int lane = threadIdx.x & 63, wv = threadIdx.x >> 6;
  int m = lane & 15, q = lane >> 4;
  int rbase = tile * 64 + wv * 16;
  int r = rbase + m;
  size_t ir = GATHER ? (size_t)bidx[r] * ADJ_ + nidx[r] : (size_t)r;
  const float* arow = in + ir * DV;

  short8v af[4];
#pragma unroll
  for (int kc = 0; kc < 4; kc++) {
    const float4* p = (const float4*)(arow + kc * 32 + q * 8);
    float4 f0 = p[0], f1 = p[1];
    union { short8v s; unsigned int u[4]; } t;
    t.u[0] = pack_bf2(f0.x, f0.y);
    t.u[1] = pack_bf2(f0.z, f0.w);
    t.u[2] = pack_bf2(f1.x, f1.y);
    t.u[3] = pack_bf2(f1.z, f1.w);
    af[kc] = t.s;
  }

  float4v acc[8];
#pragma unroll
  for (int nb = 0; nb < 8; nb++) acc[nb] = (float4v){0.f, 0.f, 0.f, 0.f};
#pragma unroll
  for (int nb = 0; nb < 8; nb++)
#pragma unroll
    for (int kc = 0; kc < 4; kc++) {
      short8v bf = *(const short8v*)(wf + (((nb * 4 + kc) * 64 + lane) << 3));
      acc[nb] = __builtin_amdgcn_mfma_f32_16x16x32_bf16(af[kc], bf, acc[nb], 0, 0, 0);
    }

#pragma unroll
  for (int nb = 0; nb < 8; nb++) {
    float bvn = HASBIAS ? bias[nb * 16 + m] : 0.f;
    int col = nb * 16 + m;
#pragma unroll
    for (int i = 0; i < 4; i++) {
      int row = rbase + q * 4 + i;
      float v = acc[nb][i] + bvn;
      if (OUTBF16) ((unsigned short*)out_)[(size_t)row * DV + col] = f2bf(v);
      else         ((float*)out_)[(size_t)row * DV + col] = v;
    }
  }
}

// ---------------- K1: fill ∪ gemm1 ∪ branch0 (no LDS anywhere) ----------------
__global__ __launch_bounds__(256)
void k1(const int* __restrict__ ei, int* __restrict__ counts,
        unsigned short* __restrict__ bucket,
        const float* __restrict__ x1, const unsigned short* __restrict__ wf1,
        unsigned int* __restrict__ t1,
        const float* __restrict__ x0, const unsigned short* __restrict__ wff,
        const float* __restrict__ bfi, float* __restrict__ out0,
        const int* __restrict__ b0, const int* __restrict__ n0i) {
  int g = blockIdx.x >> 4, rem = blockIdx.x & 15;
  if (rem < 8) { fill_part(ei, counts, bucket, g, rem); return; }
  int o = g * 8 + rem - 8;
  if (o < 1000)
    gemm_g<false, true, false>(x1, wf1, nullptr, t1, o, nullptr, nullptr);
  else if (o < 1500)
    gemm_g<true, false, true>(x0, wff, bfi, out0, o - 1000, b0, n0i);
}

// ---------------- fused aggregate + GEMM per 64-row tile ----------------
// phase1: each wave aggregates 16 rows (bias1 added) -> bf16 LDS rows (pad 272B)
// phase2: MFMA stripe from LDS A + global B-frags (+bias2) -> out
template<bool SEL, bool OUTBF16, bool BIAS2>
__global__ __launch_bounds__(256)
void agg_gemm(const unsigned int* __restrict__ x,   // bf16x2 rows [N,64]
              const int* __restrict__ counts,
              const unsigned short* __restrict__ bucket,
              const float* __restrict__ bias1,
              const unsigned short* __restrict__ wf,
              const float* __restrict__ bias2, void* __restrict__ out_,
              const int* __restrict__ bidx, const int* __restrict__ nidx) {
  __shared__ unsigned int As[64 * 68];   // 64 rows x (64 data + 4 pad) uints = 17408B
  int tid = threadIdx.x, lane = tid & 63, wv = tid >> 6;
  int tile = blockIdx.x;
  float2 bv = ((const float2*)bias1)[lane];

  for (int i = 0; i < 16; i++) {
    int rl = wv * 16 + i;
    int grow = tile * 64 + rl;
    int node = SEL ? (bidx[grow] * ADJ_ + nidx[grow]) : grow;
    int cnt = counts[node]; cnt = min(cnt, CAP);
    int mysrc = (int)bucket[(size_t)node * CAP + lane];
    float accx = bv.x, accy = bv.y;
    int d = 0;
    for (; d + 4 <= cnt; d += 4) {
      int s0 = __shfl(mysrc, d, 64);
      int s1 = __shfl(mysrc, d + 1, 64);
      int s2 = __shfl(mysrc, d + 2, 64);
      int s3 = __shfl(mysrc, d + 3, 64);
      unsigned int u0 = x[(size_t)s0 * 64 + lane];
      unsigned int u1 = x[(size_t)s1 * 64 + lane];
      unsigned int u2 = x[(size_t)s2 * 64 + lane];
      unsigned int u3 = x[(size_t)s3 * 64 + lane];
      accx += (u2f(u0 << 16) + u2f(u1 << 16)) + (u2f(u2 << 16) + u2f(u3 << 16));
      accy += (u2f(u0 & 0xffff0000u) + u2f(u1 & 0xffff0000u))
            + (u2f(u2 & 0xffff0000u) + u2f(u3 & 0xffff0000u));
    }
    for (; d < cnt; d++) {
      int s = __shfl(mysrc, d, 64);
      unsigned int u = x[(size_t)s * 64 + lane];
      accx += u2f(u << 16);
      accy += u2f(u & 0xffff0000u);
    }
    As[rl * 68 + lane] = pack_bf2(accx, accy);
  }
  __syncthreads();

  int m = lane & 15, q = lane >> 4;
  const unsigned short* As16 = (const unsigned short*)As;   // rows of 136 ushorts
  short8v af[4];
#pragma unroll
  for (int kc = 0; kc < 4; kc++)
    af[kc] = *(const short8v*)(As16 + (wv * 16 + m) * 136 + kc * 32 + q * 8);

  float4v acc[8];
#pragma unroll
  for (int nb = 0; nb < 8; nb++) acc[nb] = (float4v){0.f, 0.f, 0.f, 0.f};
#pragma unroll
  for (int nb = 0; nb < 8; nb++)
#pragma unroll
    for (int kc = 0; kc < 4; kc++) {
      short8v bf = *(const short8v*)(wf + (((nb * 4 + kc) * 64 + lane) << 3));
      acc[nb] = __builtin_amdgcn_mfma_f32_16x16x32_bf16(af[kc], bf, acc[nb], 0, 0, 0);
    }

#pragma unroll
  for (int nb = 0; nb < 8; nb++) {
    float bvn = BIAS2 ? bias2[nb * 16 + m] : 0.f;
    int col = nb * 16 + m;
#pragma unroll
    for (int i = 0; i < 4; i++) {
      int row = tile * 64 + wv * 16 + q * 4 + i;
      float v = acc[nb][i] + bvn;
      if (OUTBF16) ((unsigned short*)out_)[(size_t)row * DV + col] = f2bf(v);
      else         ((float*)out_)[(size_t)row * DV + col] = v;
    }
  }
}

extern "C" void kernel_launch(void* const* d_in, const int* in_sizes, int n_in,
                              void* d_out, int out_size, void* d_ws, size_t ws_size,
                              hipStream_t stream) {
  const float* x0  = (const float*)d_in[0];
  const float* x1  = (const float*)d_in[1];
  const int*   ei  = (const int*)  d_in[2];
  const int*   b0  = (const int*)  d_in[3];
  const int*   n0i = (const int*)  d_in[4];
  const int*   b1  = (const int*)  d_in[5];
  const int*   n1i = (const int*)  d_in[6];
  const float* W1  = (const float*)d_in[7];
  const float* bb1 = (const float*)d_in[8];
  const float* W2  = (const float*)d_in[9];
  const float* bb2 = (const float*)d_in[10];
  const float* Wl  = (const float*)d_in[11];
  const float* bl  = (const float*)d_in[12];
  const float* Wfi = (const float*)d_in[13];
  const float* bfi = (const float*)d_in[14];
  float* out = (float*)d_out;

  // ws: t1 16MB | t2 16MB | counts 256KB | bucket 8MB | wf 128KB
  unsigned int*   t1     = (unsigned int*)d_ws;
  unsigned int*   t2     = t1 + (size_t)N_ * 64;
  int*            counts = (int*)(t2 + (size_t)N_ * 64);
  unsigned short* bucket = (unsigned short*)(counts + N_);
  unsigned short* wf     = bucket + (size_t)N_ * CAP;
  unsigned short* wf1 = wf, *wf2 = wf + 16384, *wfl = wf + 32768, *wff = wf + 49152;

  // prep: frag-order all W + zero counts
  prep<<<(4 * 16384 + N_ + 255) / 256, 256, 0, stream>>>(W1, W2, Wl, Wfi, wf, counts);

  // K1: fill ∪ t1=x1@W1 ∪ out0=gather(x0)@Wfi+bfi
  k1<<<CHUNKS * 16, 256, 0, stream>>>(ei, counts, bucket, x1, wf1, t1,
                                      x0, wff, bfi, out, b0, n0i);

  // K2: t2 = (A@t1 + b1) @ W2   (bf16 out)
  agg_gemm<false, true, false><<<N_ / 64, 256, 0, stream>>>(
      t1, counts, bucket, bb1, wf2, nullptr, t2, nullptr, nullptr);

  // K3: out1 = (A@t2 + b2)[sel] @ Wl + bl   (f32 out)
  agg_gemm<true, false, true><<<M_ / 64, 256, 0, stream>>>(
      t2, counts, bucket, bb2, wfl, bl, out + (size_t)M_ * DV, b1, n1i);
}

// Round 7
// 273.305 us; speedup vs baseline: 1.1190x; 1.1190x over previous
//
#include <hip/hip_runtime.h>
#include <hip/hip_bf16.h>

// MyGNN on MI355X — round 7.
//  prep: W1,W2,Wl,Wfi -> bf16 frag-ordered global (L2-hot) + zero counts
//  K1:   fill_buckets ∪ gemm1(x1@W1->t1) ∪ br0(gather x0@Wfi+bfi->out0)   [LDS-free]
//  agg1: h = b1 + A@t1          (1 wave/row, 16-deep batched loads, bf16 out)
//  gemm2: t2 = h@W2             (LDS-free MFMA, bf16 out, aliases t1)
//  agg2: sel = b2 + A@t2 [sel]  (1 wave/slot, batched, bf16 out, aliases h)
//  br1:  out1 = sel@Wl + bl     (f32 out)
// GEMMs: mfma_f32_16x16x32_bf16, fp32 accumulate, B-frags from global (prep'd).

#define B_    64
#define ADJ_  1000
#define N_    64000
#define E_    (1 << 20)
#define M_    32000
#define DV    128
#define CAP   64
#define RANGES 8
#define RSPAN  (N_ / RANGES)   // 8000
#define CHUNKS 512
#define EPB    (E_ / CHUNKS)   // 2048

typedef __attribute__((ext_vector_type(8))) short short8v;   // 8 bf16
typedef __attribute__((ext_vector_type(4))) float float4v;

__device__ __forceinline__ float u2f(unsigned int u) {
  union { unsigned int i; float f; } x; x.i = u; return x.f;
}
__device__ __forceinline__ unsigned short f2bf(float f) {   // RNE
  union { float f; unsigned int i; } x; x.f = f;
  unsigned int r = x.i + 0x7fffu + ((x.i >> 16) & 1u);
  return (unsigned short)(r >> 16);
}
__device__ __forceinline__ unsigned int pack_bf2(float a, float b) {
  __hip_bfloat162 h = __float22bfloat162_rn(float2{a, b});
  union { __hip_bfloat162 h; unsigned int u; } c; c.h = h;
  return c.u;
}

// ---------------- prep: frag-order W -> bf16 global, zero counts ----------------
__global__ __launch_bounds__(256)
void prep(const float* __restrict__ W1, const float* __restrict__ W2,
          const float* __restrict__ Wl, const float* __restrict__ Wfi,
          unsigned short* __restrict__ wf, int* __restrict__ counts) {
  int t = blockIdx.x * 256 + threadIdx.x;
  if (t < 4 * 16384) {
    int mtx = t >> 14, g = t & 16383;
    const float* W = mtx == 0 ? W1 : mtx == 1 ? W2 : mtx == 2 ? Wl : Wfi;
    int k = g >> 7, n = g & 127;
    int addr = ((((n >> 4) * 4 + (k >> 5)) * 64 + ((k >> 3) & 3) * 16 + (n & 15)) << 3)
             + (k & 7);
    wf[mtx * 16384 + addr] = f2bf(W[g]);
  } else {
    int c = t - 65536;
    if (c < N_) counts[c] = 0;
  }
}

// ---------------- fill part: chunk c, dst-range r ----------------
__device__ __forceinline__ void fill_part(const int* __restrict__ ei,
                                          int* __restrict__ counts,
                                          unsigned short* __restrict__ bucket,
                                          int c, int r) {
  const int* srcA = ei;
  const int* dstA = ei + E_;
  int lo = r * RSPAN;
  int t4 = c * EPB + (int)threadIdx.x * 4;
  int4 d0 = *(const int4*)(dstA + t4);
  int4 s0 = *(const int4*)(srcA + t4);
  int4 d1 = *(const int4*)(dstA + t4 + 1024);
  int4 s1 = *(const int4*)(srcA + t4 + 1024);
#define PROC(D, S) do {                                                \
    if ((unsigned)((D) - lo) < (unsigned)RSPAN) {                      \
      int pos = atomicAdd(&counts[(D)], 1);                            \
      if (pos < CAP) bucket[(size_t)(D) * CAP + pos] = (unsigned short)(S); \
    } } while (0)
  PROC(d0.x, s0.x); PROC(d0.y, s0.y); PROC(d0.z, s0.z); PROC(d0.w, s0.w);
  PROC(d1.x, s1.x); PROC(d1.y, s1.y); PROC(d1.z, s1.z); PROC(d1.w, s1.w);
#undef PROC
}

// ---------------- LDS-free MFMA GEMM tile (B-frags from global) ----------------
template<bool GATHER, bool ABF16, bool OUTBF16, bool HASBIAS>
__device__ __forceinline__ void gemm_g(const void* __restrict__ in,
                                       const unsigned short* __restrict__ wf,
                                       const float* __restrict__ bias,
                                       void* __restrict__ out_, int tile,
                                       const int* __restrict__ bidx,
                                       const int* __restrict__ nidx) {
  int lane = threadIdx.x & 63, wv = threadIdx.x >> 6;
  int m = lane & 15, q = lane >> 4;
  int rbase = tile * 64 + wv * 16;
  int r = rbase + m;
  size_t ir = GATHER ? (size_t)bidx[r] * ADJ_ + nidx[r] : (size_t)r;

  short8v af[4];
  if (ABF16) {
    const unsigned short* arow = (const unsigned short*)in + ir * DV;
#pragma unroll
    for (int kc = 0; kc < 4; kc++)
      af[kc] = *(const short8v*)(arow + kc * 32 + q * 8);
  } else {
    const float* arow = (const float*)in + ir * DV;
#pragma unroll
    for (int kc = 0; kc < 4; kc++) {
      const float4* p = (const float4*)(arow + kc * 32 + q * 8);
      float4 f0 = p[0], f1 = p[1];
      union { short8v s; unsigned int u[4]; } t;
      t.u[0] = pack_bf2(f0.x, f0.y);
      t.u[1] = pack_bf2(f0.z, f0.w);
      t.u[2] = pack_bf2(f1.x, f1.y);
      t.u[3] = pack_bf2(f1.z, f1.w);
      af[kc] = t.s;
    }
  }

  float4v acc[8];
#pragma unroll
  for (int nb = 0; nb < 8; nb++) acc[nb] = (float4v){0.f, 0.f, 0.f, 0.f};
#pragma unroll
  for (int nb = 0; nb < 8; nb++)
#pragma unroll
    for (int kc = 0; kc < 4; kc++) {
      short8v bf = *(const short8v*)(wf + (((nb * 4 + kc) * 64 + lane) << 3));
      acc[nb] = __builtin_amdgcn_mfma_f32_16x16x32_bf16(af[kc], bf, acc[nb], 0, 0, 0);
    }

#pragma unroll
  for (int nb = 0; nb < 8; nb++) {
    float bvn = HASBIAS ? bias[nb * 16 + m] : 0.f;
    int col = nb * 16 + m;
#pragma unroll
    for (int i = 0; i < 4; i++) {
      int row = rbase + q * 4 + i;
      float v = acc[nb][i] + bvn;
      if (OUTBF16) ((unsigned short*)out_)[(size_t)row * DV + col] = f2bf(v);
      else         ((float*)out_)[(size_t)row * DV + col] = v;
    }
  }
}

// ---------------- K1: fill ∪ gemm1 ∪ branch0 ----------------
__global__ __launch_bounds__(256)
void k1(const int* __restrict__ ei, int* __restrict__ counts,
        unsigned short* __restrict__ bucket,
        const float* __restrict__ x1, const unsigned short* __restrict__ wf1,
        unsigned int* __restrict__ t1,
        const float* __restrict__ x0, const unsigned short* __restrict__ wff,
        const float* __restrict__ bfi, float* __restrict__ out0,
        const int* __restrict__ b0, const int* __restrict__ n0i) {
  int g = blockIdx.x >> 4, rem = blockIdx.x & 15;
  if (rem < 8) { fill_part(ei, counts, bucket, g, rem); return; }
  int o = g * 8 + rem - 8;
  if (o < 1000)
    gemm_g<false, false, true, false>(x1, wf1, nullptr, t1, o, nullptr, nullptr);
  else if (o < 1500)
    gemm_g<true, false, false, true>(x0, wff, bfi, out0, o - 1000, b0, n0i);
}

// ---------------- standalone GEMM ----------------
template<bool GATHER, bool ABF16, bool OUTBF16, bool HASBIAS>
__global__ __launch_bounds__(256)
void gemm_k(const void* __restrict__ in, const unsigned short* __restrict__ wf,
            const float* __restrict__ bias, void* __restrict__ out_,
            const int* __restrict__ bidx, const int* __restrict__ nidx) {
  gemm_g<GATHER, ABF16, OUTBF16, HASBIAS>(in, wf, bias, out_, blockIdx.x, bidx, nidx);
}

// ---------------- aggregation: one wave per row, 16-deep load batches ----------
// out[w,:] = bias + sum_{src in bucket(node)} x[src,:]   (bf16 in, bf16 out)
template<bool SEL>
__global__ __launch_bounds__(256)
void aggregate_k(const unsigned int* __restrict__ x,   // bf16x2 rows [N,64]
                 const int* __restrict__ counts,
                 const unsigned short* __restrict__ bucket,
                 const float* __restrict__ bias, unsigned int* __restrict__ out,
                 const int* __restrict__ bidx, const int* __restrict__ nidx) {
  int w    = (blockIdx.x * 256 + threadIdx.x) >> 6;
  int lane = threadIdx.x & 63;
  int node = SEL ? (bidx[w] * ADJ_ + nidx[w]) : w;
  int cnt = counts[node]; cnt = min(cnt, CAP);
  int mysrc = (int)bucket[(size_t)node * CAP + lane];
  float2 bv = ((const float2*)bias)[lane];
  float accx = bv.x, accy = bv.y;

  for (int d = 0; d < cnt; d += 16) {
    unsigned int u[16];
#pragma unroll
    for (int j = 0; j < 16; j++) {                 // 16 independent loads in flight
      int jj = min(d + j, cnt - 1);                // clamp: dup last row (cache-hit)
      int s = __shfl(mysrc, jj, 64);
      u[j] = x[(size_t)s * 64 + lane];
    }
#pragma unroll
    for (int j = 0; j < 16; j++) {
      unsigned int uv = (d + j < cnt) ? u[j] : 0u; // masked lanes add +0.0 (exact)
      accx += u2f(uv << 16);
      accy += u2f(uv & 0xffff0000u);
    }
  }
  out[(size_t)w * 64 + lane] = pack_bf2(accx, accy);
}

extern "C" void kernel_launch(void* const* d_in, const int* in_sizes, int n_in,
                              void* d_out, int out_size, void* d_ws, size_t ws_size,
                              hipStream_t stream) {
  const float* x0  = (const float*)d_in[0];
  const float* x1  = (const float*)d_in[1];
  const int*   ei  = (const int*)  d_in[2];
  const int*   b0  = (const int*)  d_in[3];
  const int*   n0i = (const int*)  d_in[4];
  const int*   b1  = (const int*)  d_in[5];
  const int*   n1i = (const int*)  d_in[6];
  const float* W1  = (const float*)d_in[7];
  const float* bb1 = (const float*)d_in[8];
  const float* W2  = (const float*)d_in[9];
  const float* bb2 = (const float*)d_in[10];
  const float* Wl  = (const float*)d_in[11];
  const float* bl  = (const float*)d_in[12];
  const float* Wfi = (const float*)d_in[13];
  const float* bfi = (const float*)d_in[14];
  float* out = (float*)d_out;

  // ws: bufA 16MB | bufB 16MB | counts 256KB | bucket 8MB | wf 128KB
  unsigned int*   bufA   = (unsigned int*)d_ws;           // t1, then t2
  unsigned int*   bufB   = bufA + (size_t)N_ * 64;        // h, then sel
  int*            counts = (int*)(bufB + (size_t)N_ * 64);
  unsigned short* bucket = (unsigned short*)(counts + N_);
  unsigned short* wf     = bucket + (size_t)N_ * CAP;
  unsigned short* wf1 = wf, *wf2 = wf + 16384, *wfl = wf + 32768, *wff = wf + 49152;

  // prep: frag-order all W + zero counts
  prep<<<(4 * 16384 + N_ + 255) / 256, 256, 0, stream>>>(W1, W2, Wl, Wfi, wf, counts);

  // K1: fill ∪ t1=x1@W1 ∪ out0=gather(x0)@Wfi+bfi
  k1<<<CHUNKS * 16, 256, 0, stream>>>(ei, counts, bucket, x1, wf1, bufA,
                                      x0, wff, bfi, out, b0, n0i);

  // h = b1 + A@t1   (bf16)
  aggregate_k<false><<<N_ / 4, 256, 0, stream>>>(bufA, counts, bucket, bb1,
                                                 bufB, nullptr, nullptr);
  // t2 = h@W2       (bf16, into bufA)
  gemm_k<false, true, true, false><<<N_ / 64, 256, 0, stream>>>(bufB, wf2, nullptr,
                                                                bufA, nullptr, nullptr);
  // sel = b2 + A@t2 at selected nodes  (bf16, into bufB)
  aggregate_k<true><<<M_ / 4, 256, 0, stream>>>(bufA, counts, bucket, bb2,
                                                bufB, b1, n1i);
  // out1 = sel@Wl + bl  (f32)
  gemm_k<false, true, false, true><<<M_ / 64, 256, 0, stream>>>(bufB, wfl, bl,
                                                                out + (size_t)M_ * DV,
                                                                nullptr, nullptr);
}